// Round 5
// baseline (4598.973 us; speedup 1.0000x reference)
//
#include <hip/hip_runtime.h>
#include <math.h>

#define BB 512
#define TT 2048
#define HH 64

__device__ __forceinline__ float sigmoid_fast(float x) {
    float e = __expf(-x);
    return __builtin_amdgcn_rcpf(1.0f + e);
}
__device__ __forceinline__ float tanh_fast(float x) {
    float e = __expf(-2.0f * x);
    return fmaf(2.0f, __builtin_amdgcn_rcpf(1.0f + e), -1.0f);
}

// 512 threads = 8 waves; TWO blocks per CU run concurrently (one grid round),
// so block A's barrier/LDS-latency stalls are filled by block B's waves.
// (Round-4 lesson: one 16-wave block in lockstep pegged at VALUBusy=61%,
// 2400 cyc/step vs ~1300 issue cyc -> latency-bound, not reload-bound.)
// Wave w owns gate rows [32w, 32w+32); lane half q=l>>5 owns K-slice
// [32q, 32q+32). 96 weight floats/thread pinned in VGPRs (~112 total, fits
// the 128 cap from waves_per_eu(4,4); round 4 proved pins hold: 53 live->52).
__global__ __launch_bounds__(512) __attribute__((amdgpu_waves_per_eu(4, 4)))
void lstm_fused_kernel(const float* __restrict__ x,      // [B,T]
                       const float* __restrict__ w_ih0,  // [256,1]
                       const float* __restrict__ w_hh0,  // [256,64]
                       const float* __restrict__ b_ih0,  // [256]
                       const float* __restrict__ b_hh0,  // [256]
                       const float* __restrict__ w_ih1,  // [256,64]
                       const float* __restrict__ w_hh1,  // [256,64]
                       const float* __restrict__ b_ih1,  // [256]
                       const float* __restrict__ b_hh1,  // [256]
                       const float* __restrict__ w1, const float* __restrict__ b1,
                       const float* __restrict__ w2, const float* __restrict__ b2,
                       const float* __restrict__ w3, const float* __restrict__ b3,
                       float* __restrict__ out)          // [B,10]
{
    const int b   = blockIdx.x;
    const int tid = threadIdx.x;
    const int w   = tid >> 6;        // wave 0..7
    const int l   = tid & 63;        // lane
    const int rsub = l & 31;
    const int q   = l >> 5;          // K half 0..1
    const int row = w * 32 + rsub;   // gate row 0..255
    const int k0  = q * 32;
    const int gate = w >> 1;         // 0=i 1=f 2=g 3=o (wave-uniform)

    __shared__ __align__(16) float xs[TT];      // 8 KB
    __shared__ __align__(16) float h0s[HH];
    __shared__ __align__(16) float h1s[HH];
    __shared__ __align__(16) float acts0[256];
    __shared__ __align__(16) float acts1[256];
    __shared__ float cls[96];

    // stage x[b][*] coalesced (512 float4 = 512 threads)
    {
        const float4* xg = (const float4*)(x + (size_t)b * TT);
        float4* xl = (float4*)xs;
        xl[tid] = xg[tid];
    }

    // per-thread weight slices: 3 x 32 floats
    float w0r[32], wAr[32], wBr[32];
    {
        const float4* p0 = (const float4*)(w_hh0 + row * HH + k0);
        const float4* pa = (const float4*)(w_ih1 + row * HH + k0);
        const float4* pb = (const float4*)(w_hh1 + row * HH + k0);
        #pragma unroll
        for (int j = 0; j < 8; ++j) {
            float4 v0 = p0[j], va = pa[j], vb = pb[j];
            w0r[4*j+0]=v0.x; w0r[4*j+1]=v0.y; w0r[4*j+2]=v0.z; w0r[4*j+3]=v0.w;
            wAr[4*j+0]=va.x; wAr[4*j+1]=va.y; wAr[4*j+2]=va.z; wAr[4*j+3]=va.w;
            wBr[4*j+0]=vb.x; wBr[4*j+1]=vb.y; wBr[4*j+2]=vb.z; wBr[4*j+3]=vb.w;
        }
    }
    float bias0 = b_ih0[row] + b_hh0[row];
    float bias1 = b_ih1[row] + b_hh1[row];
    float wih0r = w_ih0[row];

    // pin in VGPRs (prevents remat/sinking into the loop)
    #pragma unroll
    for (int j = 0; j < 32; ++j) {
        asm volatile("" : "+v"(w0r[j]));
        asm volatile("" : "+v"(wAr[j]));
        asm volatile("" : "+v"(wBr[j]));
    }
    asm volatile("" : "+v"(bias0));
    asm volatile("" : "+v"(bias1));
    asm volatile("" : "+v"(wih0r));

    float c0 = 0.0f, c1 = 0.0f;      // unit l's cell state, replicated per wave
    if (tid < HH) { h0s[tid] = 0.0f; h1s[tid] = 0.0f; }
    if (tid < 256) acts1[tid] = 0.0f;   // makes deferred t=0 update a no-op
    __syncthreads();

    for (int t = 0; t < TT; ++t) {
        // ---- P1a: deferred c1/h1 update (every wave, unit = lane) ----
        {
            float gi = acts1[l], gf = acts1[64 + l], gg = acts1[128 + l], go = acts1[192 + l];
            c1 = fmaf(gf, c1, gi * gg);
            h1s[l] = go * tanh_fast(c1);   // identical values across waves
        }
        // ---- P1b: partial dots over own K-half ----
        float acc0 = 0.0f, acc1 = 0.0f;
        #pragma unroll
        for (int j = 0; j < 32; j += 4) {
            float4 h4 = *(const float4*)&h0s[k0 + j];
            acc0 = fmaf(w0r[j+0], h4.x, acc0);
            acc0 = fmaf(w0r[j+1], h4.y, acc0);
            acc0 = fmaf(w0r[j+2], h4.z, acc0);
            acc0 = fmaf(w0r[j+3], h4.w, acc0);
        }
        #pragma unroll
        for (int j = 0; j < 32; j += 4) {
            float4 h4 = *(const float4*)&h1s[k0 + j];   // own wave wrote all 64
            acc1 = fmaf(wBr[j+0], h4.x, acc1);
            acc1 = fmaf(wBr[j+1], h4.y, acc1);
            acc1 = fmaf(wBr[j+2], h4.z, acc1);
            acc1 = fmaf(wBr[j+3], h4.w, acc1);
        }
        // combine layer-0 partials across K-halves
        acc0 += __shfl_xor(acc0, 32);
        acc0 += fmaf(wih0r, xs[t], bias0);
        float a0 = (gate == 2) ? tanh_fast(acc0) : sigmoid_fast(acc0);
        if (l < 32) acts0[row] = a0;
        __syncthreads();

        // ---- P2: c0/h0 update (every wave), then layer-1 finish ----
        {
            float gi = acts0[l], gf = acts0[64 + l], gg = acts0[128 + l], go = acts0[192 + l];
            c0 = fmaf(gf, c0, gi * gg);
            h0s[l] = go * tanh_fast(c0);
        }
        #pragma unroll
        for (int j = 0; j < 32; j += 4) {
            float4 h4 = *(const float4*)&h0s[k0 + j];   // own wave wrote all 64
            acc1 = fmaf(wAr[j+0], h4.x, acc1);
            acc1 = fmaf(wAr[j+1], h4.y, acc1);
            acc1 = fmaf(wAr[j+2], h4.z, acc1);
            acc1 = fmaf(wAr[j+3], h4.w, acc1);
        }
        acc1 += __shfl_xor(acc1, 32);
        acc1 += bias1;
        float a1 = (gate == 2) ? tanh_fast(acc1) : sigmoid_fast(acc1);
        if (l < 32) acts1[row] = a1;
        __syncthreads();
    }

    // final deferred h1 update -> h_last
    if (tid < HH) {
        float gi = acts1[tid], gf = acts1[64 + tid], gg = acts1[128 + tid], go = acts1[192 + tid];
        c1 = fmaf(gf, c1, gi * gg);
        h1s[tid] = go * tanh_fast(c1);
    }
    __syncthreads();

    // ---- classifier head ----
    if (tid < 64) {
        float a = b1[tid];
        #pragma unroll 8
        for (int k = 0; k < 64; ++k) a = fmaf(w1[tid * 64 + k], h1s[k], a);
        cls[tid] = fmaxf(a, 0.0f);
    }
    __syncthreads();
    if (tid < 32) {
        float a = b2[tid];
        #pragma unroll 8
        for (int k = 0; k < 64; ++k) a = fmaf(w2[tid * 64 + k], cls[k], a);
        cls[64 + tid] = fmaxf(a, 0.0f);
    }
    __syncthreads();
    if (tid < 10) {
        float a = b3[tid];
        #pragma unroll 8
        for (int k = 0; k < 32; ++k) a = fmaf(w3[tid * 32 + k], cls[64 + k], a);
        out[b * 10 + tid] = a;
    }
}

extern "C" void kernel_launch(void* const* d_in, const int* in_sizes, int n_in,
                              void* d_out, int out_size, void* d_ws, size_t ws_size,
                              hipStream_t stream) {
    const float* x     = (const float*)d_in[0];
    const float* w_ih0 = (const float*)d_in[1];
    const float* w_hh0 = (const float*)d_in[2];
    const float* b_ih0 = (const float*)d_in[3];
    const float* b_hh0 = (const float*)d_in[4];
    const float* w_ih1 = (const float*)d_in[5];
    const float* w_hh1 = (const float*)d_in[6];
    const float* b_ih1 = (const float*)d_in[7];
    const float* b_hh1 = (const float*)d_in[8];
    const float* w1    = (const float*)d_in[9];
    const float* b1    = (const float*)d_in[10];
    const float* w2    = (const float*)d_in[11];
    const float* b2    = (const float*)d_in[12];
    const float* w3    = (const float*)d_in[13];
    const float* b3    = (const float*)d_in[14];
    float* out = (float*)d_out;

    lstm_fused_kernel<<<BB, 512, 0, stream>>>(x, w_ih0, w_hh0, b_ih0, b_hh0,
                                              w_ih1, w_hh1, b_ih1, b_hh1,
                                              w1, b1, w2, b2, w3, b3, out);
}

// Round 6
// 3760.712 us; speedup vs baseline: 1.2229x; 1.2229x over previous
//
#include <hip/hip_runtime.h>
#include <math.h>

#define BB 512
#define TT 2048
#define HH 64

__device__ __forceinline__ float sigmoid_fast(float x) {
    float e = __expf(-x);
    return __builtin_amdgcn_rcpf(1.0f + e);
}
__device__ __forceinline__ float tanh_fast(float x) {
    float e = __expf(-2.0f * x);
    return fmaf(2.0f, __builtin_amdgcn_rcpf(1.0f + e), -1.0f);
}

// 256 blocks x 1024 threads; each block processes TWO batch elements (A,B)
// with the SAME pinned weights (round-4 layout: wave w owns gate rows
// [16w,16w+16), lane quarter q owns K-slice [16q,16q+16), 48 wt floats/thr).
// Rationale (round 3 vs 4): kernel is latency/issue-bound (weights-in-VGPR
// vs weights-rematerialized ran identical), so double the independent work
// per barrier phase (A+B chains) and eliminate the second grid round.
// Round-5 lesson: 96 pinned floats spilled (VGPR=64, 23MB scratch writes) —
// stay at 48/thread.
__global__ __launch_bounds__(1024) __attribute__((amdgpu_waves_per_eu(4, 4)))
void lstm_fused_kernel(const float* __restrict__ x,      // [B,T]
                       const float* __restrict__ w_ih0,  // [256,1]
                       const float* __restrict__ w_hh0,  // [256,64]
                       const float* __restrict__ b_ih0,  // [256]
                       const float* __restrict__ b_hh0,  // [256]
                       const float* __restrict__ w_ih1,  // [256,64]
                       const float* __restrict__ w_hh1,  // [256,64]
                       const float* __restrict__ b_ih1,  // [256]
                       const float* __restrict__ b_hh1,  // [256]
                       const float* __restrict__ w1, const float* __restrict__ b1,
                       const float* __restrict__ w2, const float* __restrict__ b2,
                       const float* __restrict__ w3, const float* __restrict__ b3,
                       float* __restrict__ out)          // [B,10]
{
    const int bA  = blockIdx.x * 2;
    const int bB  = bA + 1;
    const int tid = threadIdx.x;
    const int w   = tid >> 6;        // wave 0..15
    const int l   = tid & 63;        // lane
    const int rsub = l & 15;
    const int q   = l >> 4;          // K quarter 0..3
    const int row = w * 16 + rsub;   // gate row 0..255
    const int k0  = q * 16;
    const int gate = w >> 2;         // 0=i 1=f 2=g 3=o (wave-uniform)

    __shared__ __align__(16) float xsA[TT], xsB[TT];          // 16 KB
    __shared__ __align__(16) float h0sA[HH], h0sB[HH];
    __shared__ __align__(16) float h1sA[HH], h1sB[HH];
    __shared__ __align__(16) float acts0A[256], acts0B[256];
    __shared__ __align__(16) float acts1A[256], acts1B[256];
    __shared__ float clsA[96], clsB[96];

    // stage both sequences coalesced (512 float4 each)
    {
        if (tid < 512) {
            const float4* xg = (const float4*)(x + (size_t)bA * TT);
            ((float4*)xsA)[tid] = xg[tid];
        } else {
            const float4* xg = (const float4*)(x + (size_t)bB * TT);
            ((float4*)xsB)[tid - 512] = xg[tid - 512];
        }
    }

    // per-thread weight slices: 3 x 16 floats (shared by A and B)
    float w0r[16], wAr[16], wBr[16];
    {
        const float4* p0 = (const float4*)(w_hh0 + row * HH + k0);
        const float4* pa = (const float4*)(w_ih1 + row * HH + k0);
        const float4* pb = (const float4*)(w_hh1 + row * HH + k0);
        #pragma unroll
        for (int j = 0; j < 4; ++j) {
            float4 v0 = p0[j], va = pa[j], vb = pb[j];
            w0r[4*j+0]=v0.x; w0r[4*j+1]=v0.y; w0r[4*j+2]=v0.z; w0r[4*j+3]=v0.w;
            wAr[4*j+0]=va.x; wAr[4*j+1]=va.y; wAr[4*j+2]=va.z; wAr[4*j+3]=va.w;
            wBr[4*j+0]=vb.x; wBr[4*j+1]=vb.y; wBr[4*j+2]=vb.z; wBr[4*j+3]=vb.w;
        }
    }
    float bias0 = b_ih0[row] + b_hh0[row];
    float bias1 = b_ih1[row] + b_hh1[row];
    float wih0r = w_ih0[row];

    // pin weights (round-4 proven: holds without spill at 48 floats)
    #pragma unroll
    for (int j = 0; j < 16; ++j) {
        asm volatile("" : "+v"(w0r[j]));
        asm volatile("" : "+v"(wAr[j]));
        asm volatile("" : "+v"(wBr[j]));
    }
    asm volatile("" : "+v"(bias0));
    asm volatile("" : "+v"(bias1));
    asm volatile("" : "+v"(wih0r));

    float c0A = 0.0f, c1A = 0.0f, c0B = 0.0f, c1B = 0.0f;  // unit l, replicated/wave
    if (tid < HH) { h0sA[tid] = 0.0f; h0sB[tid] = 0.0f; h1sA[tid] = 0.0f; h1sB[tid] = 0.0f; }
    if (tid < 256) { acts1A[tid] = 0.0f; acts1B[tid] = 0.0f; }  // t=0 deferred no-op
    __syncthreads();

    for (int t = 0; t < TT; ++t) {
        // ---- P1a: deferred c1/h1 updates (every wave, unit = lane) ----
        {
            float giA = acts1A[l], gfA = acts1A[64 + l], ggA = acts1A[128 + l], goA = acts1A[192 + l];
            float giB = acts1B[l], gfB = acts1B[64 + l], ggB = acts1B[128 + l], goB = acts1B[192 + l];
            c1A = fmaf(gfA, c1A, giA * ggA);
            c1B = fmaf(gfB, c1B, giB * ggB);
            h1sA[l] = goA * tanh_fast(c1A);   // identical values across waves
            h1sB[l] = goB * tanh_fast(c1B);
        }
        // ---- P1b: partial dots over own K-slice, A and B interleaved ----
        float acc0A = 0.0f, acc0B = 0.0f, acc1A = 0.0f, acc1B = 0.0f;
        #pragma unroll
        for (int j = 0; j < 16; j += 4) {
            float4 hA = *(const float4*)&h0sA[k0 + j];
            float4 hB = *(const float4*)&h0sB[k0 + j];
            acc0A = fmaf(w0r[j+0], hA.x, acc0A); acc0B = fmaf(w0r[j+0], hB.x, acc0B);
            acc0A = fmaf(w0r[j+1], hA.y, acc0A); acc0B = fmaf(w0r[j+1], hB.y, acc0B);
            acc0A = fmaf(w0r[j+2], hA.z, acc0A); acc0B = fmaf(w0r[j+2], hB.z, acc0B);
            acc0A = fmaf(w0r[j+3], hA.w, acc0A); acc0B = fmaf(w0r[j+3], hB.w, acc0B);
        }
        #pragma unroll
        for (int j = 0; j < 16; j += 4) {
            float4 hA = *(const float4*)&h1sA[k0 + j];
            float4 hB = *(const float4*)&h1sB[k0 + j];
            acc1A = fmaf(wBr[j+0], hA.x, acc1A); acc1B = fmaf(wBr[j+0], hB.x, acc1B);
            acc1A = fmaf(wBr[j+1], hA.y, acc1A); acc1B = fmaf(wBr[j+1], hB.y, acc1B);
            acc1A = fmaf(wBr[j+2], hA.z, acc1A); acc1B = fmaf(wBr[j+2], hB.z, acc1B);
            acc1A = fmaf(wBr[j+3], hA.w, acc1A); acc1B = fmaf(wBr[j+3], hB.w, acc1B);
        }
        // combine layer-0 partials across quarters
        acc0A += __shfl_xor(acc0A, 16);
        acc0B += __shfl_xor(acc0B, 16);
        acc0A += __shfl_xor(acc0A, 32);
        acc0B += __shfl_xor(acc0B, 32);
        acc0A += fmaf(wih0r, xsA[t], bias0);
        acc0B += fmaf(wih0r, xsB[t], bias0);
        float a0A = (gate == 2) ? tanh_fast(acc0A) : sigmoid_fast(acc0A);
        float a0B = (gate == 2) ? tanh_fast(acc0B) : sigmoid_fast(acc0B);
        if (l < 16) { acts0A[row] = a0A; acts0B[row] = a0B; }
        __syncthreads();

        // ---- P2: c0/h0 updates (every wave), then layer-1 finish ----
        {
            float giA = acts0A[l], gfA = acts0A[64 + l], ggA = acts0A[128 + l], goA = acts0A[192 + l];
            float giB = acts0B[l], gfB = acts0B[64 + l], ggB = acts0B[128 + l], goB = acts0B[192 + l];
            c0A = fmaf(gfA, c0A, giA * ggA);
            c0B = fmaf(gfB, c0B, giB * ggB);
            h0sA[l] = goA * tanh_fast(c0A);
            h0sB[l] = goB * tanh_fast(c0B);
        }
        #pragma unroll
        for (int j = 0; j < 16; j += 4) {
            float4 hA = *(const float4*)&h0sA[k0 + j];   // own wave wrote all 64
            float4 hB = *(const float4*)&h0sB[k0 + j];
            acc1A = fmaf(wAr[j+0], hA.x, acc1A); acc1B = fmaf(wAr[j+0], hB.x, acc1B);
            acc1A = fmaf(wAr[j+1], hA.y, acc1A); acc1B = fmaf(wAr[j+1], hB.y, acc1B);
            acc1A = fmaf(wAr[j+2], hA.z, acc1A); acc1B = fmaf(wAr[j+2], hB.z, acc1B);
            acc1A = fmaf(wAr[j+3], hA.w, acc1A); acc1B = fmaf(wAr[j+3], hB.w, acc1B);
        }
        acc1A += __shfl_xor(acc1A, 16);
        acc1B += __shfl_xor(acc1B, 16);
        acc1A += __shfl_xor(acc1A, 32);
        acc1B += __shfl_xor(acc1B, 32);
        acc1A += bias1;
        acc1B += bias1;
        float a1A = (gate == 2) ? tanh_fast(acc1A) : sigmoid_fast(acc1A);
        float a1B = (gate == 2) ? tanh_fast(acc1B) : sigmoid_fast(acc1B);
        if (l < 16) { acts1A[row] = a1A; acts1B[row] = a1B; }
        __syncthreads();
    }

    // final deferred h1 updates -> h_last
    if (tid < HH) {
        float giA = acts1A[tid], gfA = acts1A[64 + tid], ggA = acts1A[128 + tid], goA = acts1A[192 + tid];
        float giB = acts1B[tid], gfB = acts1B[64 + tid], ggB = acts1B[128 + tid], goB = acts1B[192 + tid];
        c1A = fmaf(gfA, c1A, giA * ggA);
        c1B = fmaf(gfB, c1B, giB * ggB);
        h1sA[tid] = goA * tanh_fast(c1A);
        h1sB[tid] = goB * tanh_fast(c1B);
    }
    __syncthreads();

    // ---- classifier heads: A on wave0 rows, B on wave1 rows ----
    if (tid < 64) {
        float a = b1[tid];
        #pragma unroll 8
        for (int k = 0; k < 64; ++k) a = fmaf(w1[tid * 64 + k], h1sA[k], a);
        clsA[tid] = fmaxf(a, 0.0f);
    } else if (tid < 128) {
        const int r = tid - 64;
        float a = b1[r];
        #pragma unroll 8
        for (int k = 0; k < 64; ++k) a = fmaf(w1[r * 64 + k], h1sB[k], a);
        clsB[r] = fmaxf(a, 0.0f);
    }
    __syncthreads();
    if (tid < 32) {
        float a = b2[tid];
        #pragma unroll 8
        for (int k = 0; k < 64; ++k) a = fmaf(w2[tid * 64 + k], clsA[k], a);
        clsA[64 + tid] = fmaxf(a, 0.0f);
    } else if (tid >= 64 && tid < 96) {
        const int r = tid - 64;
        float a = b2[r];
        #pragma unroll 8
        for (int k = 0; k < 64; ++k) a = fmaf(w2[r * 64 + k], clsB[k], a);
        clsB[64 + r] = fmaxf(a, 0.0f);
    }
    __syncthreads();
    if (tid < 10) {
        float a = b3[tid];
        #pragma unroll 8
        for (int k = 0; k < 32; ++k) a = fmaf(w3[tid * 32 + k], clsA[64 + k], a);
        out[bA * 10 + tid] = a;
    } else if (tid >= 64 && tid < 74) {
        const int r = tid - 64;
        float a = b3[r];
        #pragma unroll 8
        for (int k = 0; k < 32; ++k) a = fmaf(w3[r * 32 + k], clsB[64 + k], a);
        out[bB * 10 + r] = a;
    }
}

extern "C" void kernel_launch(void* const* d_in, const int* in_sizes, int n_in,
                              void* d_out, int out_size, void* d_ws, size_t ws_size,
                              hipStream_t stream) {
    const float* x     = (const float*)d_in[0];
    const float* w_ih0 = (const float*)d_in[1];
    const float* w_hh0 = (const float*)d_in[2];
    const float* b_ih0 = (const float*)d_in[3];
    const float* b_hh0 = (const float*)d_in[4];
    const float* w_ih1 = (const float*)d_in[5];
    const float* w_hh1 = (const float*)d_in[6];
    const float* b_ih1 = (const float*)d_in[7];
    const float* b_hh1 = (const float*)d_in[8];
    const float* w1    = (const float*)d_in[9];
    const float* b1    = (const float*)d_in[10];
    const float* w2    = (const float*)d_in[11];
    const float* b2    = (const float*)d_in[12];
    const float* w3    = (const float*)d_in[13];
    const float* b3    = (const float*)d_in[14];
    float* out = (float*)d_out;

    lstm_fused_kernel<<<BB / 2, 1024, 0, stream>>>(x, w_ih0, w_hh0, b_ih0, b_hh0,
                                                   w_ih1, w_hh1, b_ih1, b_hh1,
                                                   w1, b1, w2, b2, w3, b3, out);
}

// Round 7
// 3319.284 us; speedup vs baseline: 1.3855x; 1.1330x over previous
//
#include <hip/hip_runtime.h>
#include <math.h>

#define BB 512
#define TT 2048
#define HH 64

__device__ __forceinline__ float sigmoid_fast(float x) {
    float e = __expf(-x);
    return __builtin_amdgcn_rcpf(1.0f + e);
}
__device__ __forceinline__ float tanh_fast(float x) {
    float e = __expf(-2.0f * x);
    return fmaf(2.0f, __builtin_amdgcn_rcpf(1.0f + e), -1.0f);
}

// 256 blocks x 1024 threads, two batch elements (A,B) per block, row-owner
// layout (wave w owns gate rows [16w,16w+16), lane quarter q owns K-slice
// [16q,16q+16), 48 pinned weight floats/thread — rounds 4/6 proven no-spill).
//
// ROUND-7 CHANGE: fully-deferred two-stage software pipeline -> ONE barrier
// per timestep (round 6 paid two). At iter t every wave redundantly applies
//   acts0(t-1) -> h0(t-1),   acts1(t-1)=gates1(t-2) -> h1(t-2)
// then computes gates0(t) = Whh0.h0(t-1) + wih0*x[t]
//           and gates1(t-1) = Wih1.h0(t-1) + Whh1.h1(t-2)
// in the same phase. acts are ping-pong buffered (read [p], write [p^1]);
// h arrays are benign-redundant (every wave writes all 64 units, identical
// values). Pipeline depth 2 -> TT+2 iters; acts1 write zeroed at t==0 so
// h1(-1)==0; xs padded with 2 zeros for the drain iters.
__global__ __launch_bounds__(1024) __attribute__((amdgpu_waves_per_eu(4, 4)))
void lstm_fused_kernel(const float* __restrict__ x,      // [B,T]
                       const float* __restrict__ w_ih0,  // [256,1]
                       const float* __restrict__ w_hh0,  // [256,64]
                       const float* __restrict__ b_ih0,  // [256]
                       const float* __restrict__ b_hh0,  // [256]
                       const float* __restrict__ w_ih1,  // [256,64]
                       const float* __restrict__ w_hh1,  // [256,64]
                       const float* __restrict__ b_ih1,  // [256]
                       const float* __restrict__ b_hh1,  // [256]
                       const float* __restrict__ w1, const float* __restrict__ b1,
                       const float* __restrict__ w2, const float* __restrict__ b2,
                       const float* __restrict__ w3, const float* __restrict__ b3,
                       float* __restrict__ out)          // [B,10]
{
    const int bA  = blockIdx.x * 2;
    const int bB  = bA + 1;
    const int tid = threadIdx.x;
    const int w   = tid >> 6;        // wave 0..15
    const int l   = tid & 63;        // lane
    const int rsub = l & 15;
    const int q   = l >> 4;          // K quarter 0..3
    const int row = w * 16 + rsub;   // gate row 0..255
    const int k0  = q * 16;
    const int gate = w >> 2;         // 0=i 1=f 2=g 3=o (wave-uniform)

    __shared__ __align__(16) float xsA[TT + 2], xsB[TT + 2];
    __shared__ __align__(16) float h0sA[HH], h0sB[HH];
    __shared__ __align__(16) float h1sA[HH], h1sB[HH];
    __shared__ __align__(16) float acts0A[2][256], acts0B[2][256];
    __shared__ __align__(16) float acts1A[2][256], acts1B[2][256];
    __shared__ float clsA[96], clsB[96];

    // stage both sequences coalesced (512 float4 each) + zero-pad tails
    {
        if (tid < 512) {
            const float4* xg = (const float4*)(x + (size_t)bA * TT);
            ((float4*)xsA)[tid] = xg[tid];
        } else {
            const float4* xg = (const float4*)(x + (size_t)bB * TT);
            ((float4*)xsB)[tid - 512] = xg[tid - 512];
        }
        if (tid < 2) { xsA[TT + tid] = 0.0f; xsB[TT + tid] = 0.0f; }
    }

    // per-thread weight slices: 3 x 16 floats (shared by A and B)
    float w0r[16], wAr[16], wBr[16];
    {
        const float4* p0 = (const float4*)(w_hh0 + row * HH + k0);
        const float4* pa = (const float4*)(w_ih1 + row * HH + k0);
        const float4* pb = (const float4*)(w_hh1 + row * HH + k0);
        #pragma unroll
        for (int j = 0; j < 4; ++j) {
            float4 v0 = p0[j], va = pa[j], vb = pb[j];
            w0r[4*j+0]=v0.x; w0r[4*j+1]=v0.y; w0r[4*j+2]=v0.z; w0r[4*j+3]=v0.w;
            wAr[4*j+0]=va.x; wAr[4*j+1]=va.y; wAr[4*j+2]=va.z; wAr[4*j+3]=va.w;
            wBr[4*j+0]=vb.x; wBr[4*j+1]=vb.y; wBr[4*j+2]=vb.z; wBr[4*j+3]=vb.w;
        }
    }
    float bias0 = b_ih0[row] + b_hh0[row];
    float bias1 = b_ih1[row] + b_hh1[row];
    float wih0r = w_ih0[row];

    // pin weights (rounds 4/6 proven: holds without spill at 48 floats)
    #pragma unroll
    for (int j = 0; j < 16; ++j) {
        asm volatile("" : "+v"(w0r[j]));
        asm volatile("" : "+v"(wAr[j]));
        asm volatile("" : "+v"(wBr[j]));
    }
    asm volatile("" : "+v"(bias0));
    asm volatile("" : "+v"(bias1));
    asm volatile("" : "+v"(wih0r));

    float c0A = 0.0f, c1A = 0.0f, c0B = 0.0f, c1B = 0.0f;  // unit l, replicated/wave
    if (tid < HH) { h0sA[tid] = 0.0f; h0sB[tid] = 0.0f; h1sA[tid] = 0.0f; h1sB[tid] = 0.0f; }
    if (tid < 256) {   // parity-0 acts are read at iter 0: must be zero
        acts0A[0][tid] = 0.0f; acts0B[0][tid] = 0.0f;
        acts1A[0][tid] = 0.0f; acts1B[0][tid] = 0.0f;
    }
    __syncthreads();

    for (int t = 0; t < TT + 2; ++t) {
        const int p = t & 1;
        // ---- deferred updates (every wave, unit = lane): h0(t-1), h1(t-2) ----
        {
            float gi = acts0A[p][l], gf = acts0A[p][64 + l], gg = acts0A[p][128 + l], go = acts0A[p][192 + l];
            c0A = fmaf(gf, c0A, gi * gg);
            h0sA[l] = go * tanh_fast(c0A);
        }
        {
            float gi = acts0B[p][l], gf = acts0B[p][64 + l], gg = acts0B[p][128 + l], go = acts0B[p][192 + l];
            c0B = fmaf(gf, c0B, gi * gg);
            h0sB[l] = go * tanh_fast(c0B);
        }
        {
            float gi = acts1A[p][l], gf = acts1A[p][64 + l], gg = acts1A[p][128 + l], go = acts1A[p][192 + l];
            c1A = fmaf(gf, c1A, gi * gg);
            h1sA[l] = go * tanh_fast(c1A);
        }
        {
            float gi = acts1B[p][l], gf = acts1B[p][64 + l], gg = acts1B[p][128 + l], go = acts1B[p][192 + l];
            c1B = fmaf(gf, c1B, gi * gg);
            h1sB[l] = go * tanh_fast(c1B);
        }

        // ---- dots: gates0(t) and gates1(t-1), partials over own K-slice ----
        float acc0A = 0.0f, acc0B = 0.0f, acc1A = 0.0f, acc1B = 0.0f;
        #pragma unroll
        for (int j = 0; j < 16; j += 4) {
            float4 hA = *(const float4*)&h0sA[k0 + j];   // h0(t-1), own wave wrote all 64
            float4 hB = *(const float4*)&h0sB[k0 + j];
            acc0A = fmaf(w0r[j+0], hA.x, acc0A); acc0B = fmaf(w0r[j+0], hB.x, acc0B);
            acc0A = fmaf(w0r[j+1], hA.y, acc0A); acc0B = fmaf(w0r[j+1], hB.y, acc0B);
            acc0A = fmaf(w0r[j+2], hA.z, acc0A); acc0B = fmaf(w0r[j+2], hB.z, acc0B);
            acc0A = fmaf(w0r[j+3], hA.w, acc0A); acc0B = fmaf(w0r[j+3], hB.w, acc0B);
            acc1A = fmaf(wAr[j+0], hA.x, acc1A); acc1B = fmaf(wAr[j+0], hB.x, acc1B);
            acc1A = fmaf(wAr[j+1], hA.y, acc1A); acc1B = fmaf(wAr[j+1], hB.y, acc1B);
            acc1A = fmaf(wAr[j+2], hA.z, acc1A); acc1B = fmaf(wAr[j+2], hB.z, acc1B);
            acc1A = fmaf(wAr[j+3], hA.w, acc1A); acc1B = fmaf(wAr[j+3], hB.w, acc1B);
        }
        #pragma unroll
        for (int j = 0; j < 16; j += 4) {
            float4 hA = *(const float4*)&h1sA[k0 + j];   // h1(t-2)
            float4 hB = *(const float4*)&h1sB[k0 + j];
            acc1A = fmaf(wBr[j+0], hA.x, acc1A); acc1B = fmaf(wBr[j+0], hB.x, acc1B);
            acc1A = fmaf(wBr[j+1], hA.y, acc1A); acc1B = fmaf(wBr[j+1], hB.y, acc1B);
            acc1A = fmaf(wBr[j+2], hA.z, acc1A); acc1B = fmaf(wBr[j+2], hB.z, acc1B);
            acc1A = fmaf(wBr[j+3], hA.w, acc1A); acc1B = fmaf(wBr[j+3], hB.w, acc1B);
        }

        // combine partials across quarters
        acc0A += __shfl_xor(acc0A, 16);
        acc0B += __shfl_xor(acc0B, 16);
        acc1A += __shfl_xor(acc1A, 16);
        acc1B += __shfl_xor(acc1B, 16);
        acc0A += __shfl_xor(acc0A, 32);
        acc0B += __shfl_xor(acc0B, 32);
        acc1A += __shfl_xor(acc1A, 32);
        acc1B += __shfl_xor(acc1B, 32);
        acc0A += fmaf(wih0r, xsA[t], bias0);
        acc0B += fmaf(wih0r, xsB[t], bias0);
        acc1A += bias1;
        acc1B += bias1;

        float a0A = (gate == 2) ? tanh_fast(acc0A) : sigmoid_fast(acc0A);
        float a0B = (gate == 2) ? tanh_fast(acc0B) : sigmoid_fast(acc0B);
        float a1A = (gate == 2) ? tanh_fast(acc1A) : sigmoid_fast(acc1A);
        float a1B = (gate == 2) ? tanh_fast(acc1B) : sigmoid_fast(acc1B);
        if (t == 0) { a1A = 0.0f; a1B = 0.0f; }   // enforce h1(-1) == 0

        if (l < 16) {
            acts0A[p ^ 1][row] = a0A;
            acts0B[p ^ 1][row] = a0B;
            acts1A[p ^ 1][row] = a1A;
            acts1B[p ^ 1][row] = a1B;
        }
        __syncthreads();
    }
    // h1sA/h1sB now hold h1(TT-1) = h_last

    // ---- classifier heads: A on wave0 rows, B on wave1 rows ----
    if (tid < 64) {
        float a = b1[tid];
        #pragma unroll 8
        for (int k = 0; k < 64; ++k) a = fmaf(w1[tid * 64 + k], h1sA[k], a);
        clsA[tid] = fmaxf(a, 0.0f);
    } else if (tid < 128) {
        const int r = tid - 64;
        float a = b1[r];
        #pragma unroll 8
        for (int k = 0; k < 64; ++k) a = fmaf(w1[r * 64 + k], h1sB[k], a);
        clsB[r] = fmaxf(a, 0.0f);
    }
    __syncthreads();
    if (tid < 32) {
        float a = b2[tid];
        #pragma unroll 8
        for (int k = 0; k < 64; ++k) a = fmaf(w2[tid * 64 + k], clsA[k], a);
        clsA[64 + tid] = fmaxf(a, 0.0f);
    } else if (tid >= 64 && tid < 96) {
        const int r = tid - 64;
        float a = b2[r];
        #pragma unroll 8
        for (int k = 0; k < 64; ++k) a = fmaf(w2[r * 64 + k], clsB[k], a);
        clsB[64 + r] = fmaxf(a, 0.0f);
    }
    __syncthreads();
    if (tid < 10) {
        float a = b3[tid];
        #pragma unroll 8
        for (int k = 0; k < 32; ++k) a = fmaf(w3[tid * 32 + k], clsA[64 + k], a);
        out[bA * 10 + tid] = a;
    } else if (tid >= 64 && tid < 74) {
        const int r = tid - 64;
        float a = b3[r];
        #pragma unroll 8
        for (int k = 0; k < 32; ++k) a = fmaf(w3[r * 32 + k], clsB[64 + k], a);
        out[bB * 10 + r] = a;
    }
}

extern "C" void kernel_launch(void* const* d_in, const int* in_sizes, int n_in,
                              void* d_out, int out_size, void* d_ws, size_t ws_size,
                              hipStream_t stream) {
    const float* x     = (const float*)d_in[0];
    const float* w_ih0 = (const float*)d_in[1];
    const float* w_hh0 = (const float*)d_in[2];
    const float* b_ih0 = (const float*)d_in[3];
    const float* b_hh0 = (const float*)d_in[4];
    const float* w_ih1 = (const float*)d_in[5];
    const float* w_hh1 = (const float*)d_in[6];
    const float* b_ih1 = (const float*)d_in[7];
    const float* b_hh1 = (const float*)d_in[8];
    const float* w1    = (const float*)d_in[9];
    const float* b1    = (const float*)d_in[10];
    const float* w2    = (const float*)d_in[11];
    const float* b2    = (const float*)d_in[12];
    const float* w3    = (const float*)d_in[13];
    const float* b3    = (const float*)d_in[14];
    float* out = (float*)d_out;

    lstm_fused_kernel<<<BB / 2, 1024, 0, stream>>>(x, w_ih0, w_hh0, b_ih0, b_hh0,
                                                   w_ih1, w_hh1, b_ih1, b_hh1,
                                                   w1, b1, w2, b2, w3, b3, out);
}

// Round 8
// 3025.430 us; speedup vs baseline: 1.5201x; 1.0971x over previous
//
#include <hip/hip_runtime.h>
#include <math.h>

#define BB 512
#define TT 2048
#define HH 64

typedef _Float16 half2_t __attribute__((ext_vector_type(2)));

__device__ __forceinline__ float sigmoid_fast(float x) {
    float e = __expf(-x);
    return __builtin_amdgcn_rcpf(1.0f + e);
}
__device__ __forceinline__ float tanh_fast(float x) {
    float e = __expf(-2.0f * x);
    return fmaf(2.0f, __builtin_amdgcn_rcpf(1.0f + e), -1.0f);
}
__device__ __forceinline__ float fdot2u(unsigned int a, unsigned int b, float c) {
    return __builtin_amdgcn_fdot2(__builtin_bit_cast(half2_t, a),
                                  __builtin_bit_cast(half2_t, b), c, false);
}
__device__ __forceinline__ unsigned int pack2(float a, float b) {
    half2_t h; h[0] = (_Float16)a; h[1] = (_Float16)b;
    return __builtin_bit_cast(unsigned int, h);
}

// 256 blocks x 1024 threads, two batch elements (A,B), row-owner layout
// (wave w owns gate rows [16w,16w+16), lane quarter q owns K [16q,16q+16)),
// single-barrier deferred pipeline (round 7). ROUND-8 CHANGE: dots via
// v_dot2_f32_f16 — h and weights stored as packed fp16 pairs, accumulate in
// f32 (c-state / gates / acts stay f32). 96 fma -> 48 fdot2 per thread-iter,
// h LDS reads halve. Weights = 24 pinned uint regs (vs 48 floats) per thread.
__global__ __launch_bounds__(1024) __attribute__((amdgpu_waves_per_eu(4, 4)))
void lstm_fused_kernel(const float* __restrict__ x,      // [B,T]
                       const float* __restrict__ w_ih0,  // [256,1]
                       const float* __restrict__ w_hh0,  // [256,64]
                       const float* __restrict__ b_ih0,  // [256]
                       const float* __restrict__ b_hh0,  // [256]
                       const float* __restrict__ w_ih1,  // [256,64]
                       const float* __restrict__ w_hh1,  // [256,64]
                       const float* __restrict__ b_ih1,  // [256]
                       const float* __restrict__ b_hh1,  // [256]
                       const float* __restrict__ w1, const float* __restrict__ b1,
                       const float* __restrict__ w2, const float* __restrict__ b2,
                       const float* __restrict__ w3, const float* __restrict__ b3,
                       float* __restrict__ out)          // [B,10]
{
    const int bA  = blockIdx.x * 2;
    const int bB  = bA + 1;
    const int tid = threadIdx.x;
    const int w   = tid >> 6;        // wave 0..15
    const int l   = tid & 63;        // lane
    const int rsub = l & 15;
    const int q   = l >> 4;          // K quarter 0..3
    const int row = w * 16 + rsub;   // gate row 0..255
    const int k0  = q * 16;          // K base (element index)
    const int gate = w >> 2;         // 0=i 1=f 2=g 3=o (wave-uniform)

    __shared__ __align__(16) float xsA[TT + 2], xsB[TT + 2];
    __shared__ __align__(16) _Float16 h0sA[HH], h0sB[HH];
    __shared__ __align__(16) _Float16 h1sA[HH], h1sB[HH];
    __shared__ __align__(16) float acts0A[2][256], acts0B[2][256];
    __shared__ __align__(16) float acts1A[2][256], acts1B[2][256];
    __shared__ float clsA[96], clsB[96];

    // stage both sequences coalesced (512 float4 each) + zero-pad tails
    {
        if (tid < 512) {
            const float4* xg = (const float4*)(x + (size_t)bA * TT);
            ((float4*)xsA)[tid] = xg[tid];
        } else {
            const float4* xg = (const float4*)(x + (size_t)bB * TT);
            ((float4*)xsB)[tid - 512] = xg[tid - 512];
        }
        if (tid < 2) { xsA[TT + tid] = 0.0f; xsB[TT + tid] = 0.0f; }
    }

    // per-thread weight slices: 3 x 8 packed-fp16 uints (shared by A and B)
    unsigned int wp0[8], wpA[8], wpB[8];
    {
        const float4* p0 = (const float4*)(w_hh0 + row * HH + k0);
        const float4* pa = (const float4*)(w_ih1 + row * HH + k0);
        const float4* pb = (const float4*)(w_hh1 + row * HH + k0);
        #pragma unroll
        for (int j = 0; j < 4; ++j) {
            float4 v0 = p0[j], va = pa[j], vb = pb[j];
            wp0[2*j+0] = pack2(v0.x, v0.y); wp0[2*j+1] = pack2(v0.z, v0.w);
            wpA[2*j+0] = pack2(va.x, va.y); wpA[2*j+1] = pack2(va.z, va.w);
            wpB[2*j+0] = pack2(vb.x, vb.y); wpB[2*j+1] = pack2(vb.z, vb.w);
        }
    }
    float bias0 = b_ih0[row] + b_hh0[row];
    float bias1 = b_ih1[row] + b_hh1[row];
    float wih0r = w_ih0[row];

    // pin packed weights (rounds 4/6/7 proven pattern; prevents remat/sink)
    #pragma unroll
    for (int j = 0; j < 8; ++j) {
        asm volatile("" : "+v"(wp0[j]));
        asm volatile("" : "+v"(wpA[j]));
        asm volatile("" : "+v"(wpB[j]));
    }
    asm volatile("" : "+v"(bias0));
    asm volatile("" : "+v"(bias1));
    asm volatile("" : "+v"(wih0r));

    float c0A = 0.0f, c1A = 0.0f, c0B = 0.0f, c1B = 0.0f;  // unit l, replicated/wave
    if (tid < HH) {
        h0sA[tid] = (_Float16)0.0f; h0sB[tid] = (_Float16)0.0f;
        h1sA[tid] = (_Float16)0.0f; h1sB[tid] = (_Float16)0.0f;
    }
    if (tid < 256) {   // parity-0 acts are read at iter 0: must be zero
        acts0A[0][tid] = 0.0f; acts0B[0][tid] = 0.0f;
        acts1A[0][tid] = 0.0f; acts1B[0][tid] = 0.0f;
    }
    __syncthreads();

    for (int t = 0; t < TT + 2; ++t) {
        const int p = t & 1;
        // ---- deferred updates (every wave, unit = lane): h0(t-1), h1(t-2) ----
        {
            float gi = acts0A[p][l], gf = acts0A[p][64 + l], gg = acts0A[p][128 + l], go = acts0A[p][192 + l];
            c0A = fmaf(gf, c0A, gi * gg);
            h0sA[l] = (_Float16)(go * tanh_fast(c0A));
        }
        {
            float gi = acts0B[p][l], gf = acts0B[p][64 + l], gg = acts0B[p][128 + l], go = acts0B[p][192 + l];
            c0B = fmaf(gf, c0B, gi * gg);
            h0sB[l] = (_Float16)(go * tanh_fast(c0B));
        }
        {
            float gi = acts1A[p][l], gf = acts1A[p][64 + l], gg = acts1A[p][128 + l], go = acts1A[p][192 + l];
            c1A = fmaf(gf, c1A, gi * gg);
            h1sA[l] = (_Float16)(go * tanh_fast(c1A));
        }
        {
            float gi = acts1B[p][l], gf = acts1B[p][64 + l], gg = acts1B[p][128 + l], go = acts1B[p][192 + l];
            c1B = fmaf(gf, c1B, gi * gg);
            h1sB[l] = (_Float16)(go * tanh_fast(c1B));
        }

        // ---- dots: gates0(t) and gates1(t-1) via packed-fp16 dot2 ----
        float acc0A = 0.0f, acc0B = 0.0f, acc1A = 0.0f, acc1B = 0.0f;
        {
            const uint4 uA0 = *(const uint4*)&h0sA[k0];       // h0(t-1)[k0..k0+7]
            const uint4 uA1 = *(const uint4*)&h0sA[k0 + 8];
            const uint4 uB0 = *(const uint4*)&h0sB[k0];
            const uint4 uB1 = *(const uint4*)&h0sB[k0 + 8];
            acc0A = fdot2u(wp0[0], uA0.x, acc0A); acc0B = fdot2u(wp0[0], uB0.x, acc0B);
            acc0A = fdot2u(wp0[1], uA0.y, acc0A); acc0B = fdot2u(wp0[1], uB0.y, acc0B);
            acc0A = fdot2u(wp0[2], uA0.z, acc0A); acc0B = fdot2u(wp0[2], uB0.z, acc0B);
            acc0A = fdot2u(wp0[3], uA0.w, acc0A); acc0B = fdot2u(wp0[3], uB0.w, acc0B);
            acc0A = fdot2u(wp0[4], uA1.x, acc0A); acc0B = fdot2u(wp0[4], uB1.x, acc0B);
            acc0A = fdot2u(wp0[5], uA1.y, acc0A); acc0B = fdot2u(wp0[5], uB1.y, acc0B);
            acc0A = fdot2u(wp0[6], uA1.z, acc0A); acc0B = fdot2u(wp0[6], uB1.z, acc0B);
            acc0A = fdot2u(wp0[7], uA1.w, acc0A); acc0B = fdot2u(wp0[7], uB1.w, acc0B);
            acc1A = fdot2u(wpA[0], uA0.x, acc1A); acc1B = fdot2u(wpA[0], uB0.x, acc1B);
            acc1A = fdot2u(wpA[1], uA0.y, acc1A); acc1B = fdot2u(wpA[1], uB0.y, acc1B);
            acc1A = fdot2u(wpA[2], uA0.z, acc1A); acc1B = fdot2u(wpA[2], uB0.z, acc1B);
            acc1A = fdot2u(wpA[3], uA0.w, acc1A); acc1B = fdot2u(wpA[3], uB0.w, acc1B);
            acc1A = fdot2u(wpA[4], uA1.x, acc1A); acc1B = fdot2u(wpA[4], uB1.x, acc1B);
            acc1A = fdot2u(wpA[5], uA1.y, acc1A); acc1B = fdot2u(wpA[5], uB1.y, acc1B);
            acc1A = fdot2u(wpA[6], uA1.z, acc1A); acc1B = fdot2u(wpA[6], uB1.z, acc1B);
            acc1A = fdot2u(wpA[7], uA1.w, acc1A); acc1B = fdot2u(wpA[7], uB1.w, acc1B);
        }
        {
            const uint4 uA0 = *(const uint4*)&h1sA[k0];       // h1(t-2)[k0..]
            const uint4 uA1 = *(const uint4*)&h1sA[k0 + 8];
            const uint4 uB0 = *(const uint4*)&h1sB[k0];
            const uint4 uB1 = *(const uint4*)&h1sB[k0 + 8];
            acc1A = fdot2u(wpB[0], uA0.x, acc1A); acc1B = fdot2u(wpB[0], uB0.x, acc1B);
            acc1A = fdot2u(wpB[1], uA0.y, acc1A); acc1B = fdot2u(wpB[1], uB0.y, acc1B);
            acc1A = fdot2u(wpB[2], uA0.z, acc1A); acc1B = fdot2u(wpB[2], uB0.z, acc1B);
            acc1A = fdot2u(wpB[3], uA0.w, acc1A); acc1B = fdot2u(wpB[3], uB0.w, acc1B);
            acc1A = fdot2u(wpB[4], uA1.x, acc1A); acc1B = fdot2u(wpB[4], uB1.x, acc1B);
            acc1A = fdot2u(wpB[5], uA1.y, acc1A); acc1B = fdot2u(wpB[5], uB1.y, acc1B);
            acc1A = fdot2u(wpB[6], uA1.z, acc1A); acc1B = fdot2u(wpB[6], uB1.z, acc1B);
            acc1A = fdot2u(wpB[7], uA1.w, acc1A); acc1B = fdot2u(wpB[7], uB1.w, acc1B);
        }

        // combine partials across quarters
        acc0A += __shfl_xor(acc0A, 16);
        acc0B += __shfl_xor(acc0B, 16);
        acc1A += __shfl_xor(acc1A, 16);
        acc1B += __shfl_xor(acc1B, 16);
        acc0A += __shfl_xor(acc0A, 32);
        acc0B += __shfl_xor(acc0B, 32);
        acc1A += __shfl_xor(acc1A, 32);
        acc1B += __shfl_xor(acc1B, 32);
        acc0A += fmaf(wih0r, xsA[t], bias0);
        acc0B += fmaf(wih0r, xsB[t], bias0);
        acc1A += bias1;
        acc1B += bias1;

        float a0A = (gate == 2) ? tanh_fast(acc0A) : sigmoid_fast(acc0A);
        float a0B = (gate == 2) ? tanh_fast(acc0B) : sigmoid_fast(acc0B);
        float a1A = (gate == 2) ? tanh_fast(acc1A) : sigmoid_fast(acc1A);
        float a1B = (gate == 2) ? tanh_fast(acc1B) : sigmoid_fast(acc1B);
        if (t == 0) { a1A = 0.0f; a1B = 0.0f; }   // enforce h1(-1) == 0

        if (l < 16) {
            acts0A[p ^ 1][row] = a0A;
            acts0B[p ^ 1][row] = a0B;
            acts1A[p ^ 1][row] = a1A;
            acts1B[p ^ 1][row] = a1B;
        }
        __syncthreads();
    }
    // h1sA/h1sB now hold h1(TT-1) = h_last (fp16)

    // ---- classifier heads: A on wave0 rows, B on wave1 rows ----
    if (tid < 64) {
        float a = b1[tid];
        #pragma unroll 8
        for (int k = 0; k < 64; ++k) a = fmaf(w1[tid * 64 + k], (float)h1sA[k], a);
        clsA[tid] = fmaxf(a, 0.0f);
    } else if (tid < 128) {
        const int r = tid - 64;
        float a = b1[r];
        #pragma unroll 8
        for (int k = 0; k < 64; ++k) a = fmaf(w1[r * 64 + k], (float)h1sB[k], a);
        clsB[r] = fmaxf(a, 0.0f);
    }
    __syncthreads();
    if (tid < 32) {
        float a = b2[tid];
        #pragma unroll 8
        for (int k = 0; k < 64; ++k) a = fmaf(w2[tid * 64 + k], clsA[k], a);
        clsA[64 + tid] = fmaxf(a, 0.0f);
    } else if (tid >= 64 && tid < 96) {
        const int r = tid - 64;
        float a = b2[r];
        #pragma unroll 8
        for (int k = 0; k < 64; ++k) a = fmaf(w2[r * 64 + k], clsB[k], a);
        clsB[64 + r] = fmaxf(a, 0.0f);
    }
    __syncthreads();
    if (tid < 10) {
        float a = b3[tid];
        #pragma unroll 8
        for (int k = 0; k < 32; ++k) a = fmaf(w3[tid * 32 + k], clsA[64 + k], a);
        out[bA * 10 + tid] = a;
    } else if (tid >= 64 && tid < 74) {
        const int r = tid - 64;
        float a = b3[r];
        #pragma unroll 8
        for (int k = 0; k < 32; ++k) a = fmaf(w3[r * 32 + k], clsB[64 + k], a);
        out[bB * 10 + r] = a;
    }
}

extern "C" void kernel_launch(void* const* d_in, const int* in_sizes, int n_in,
                              void* d_out, int out_size, void* d_ws, size_t ws_size,
                              hipStream_t stream) {
    const float* x     = (const float*)d_in[0];
    const float* w_ih0 = (const float*)d_in[1];
    const float* w_hh0 = (const float*)d_in[2];
    const float* b_ih0 = (const float*)d_in[3];
    const float* b_hh0 = (const float*)d_in[4];
    const float* w_ih1 = (const float*)d_in[5];
    const float* w_hh1 = (const float*)d_in[6];
    const float* b_ih1 = (const float*)d_in[7];
    const float* b_hh1 = (const float*)d_in[8];
    const float* w1    = (const float*)d_in[9];
    const float* b1    = (const float*)d_in[10];
    const float* w2    = (const float*)d_in[11];
    const float* b2    = (const float*)d_in[12];
    const float* w3    = (const float*)d_in[13];
    const float* b3    = (const float*)d_in[14];
    float* out = (float*)d_out;

    lstm_fused_kernel<<<BB / 2, 1024, 0, stream>>>(x, w_ih0, w_hh0, b_ih0, b_hh0,
                                                   w_ih1, w_hh1, b_ih1, b_hh1,
                                                   w1, b1, w2, b2, w3, b3, out);
}

// Round 9
// 1652.060 us; speedup vs baseline: 2.7838x; 1.8313x over previous
//
#include <hip/hip_runtime.h>
#include <math.h>

#define TT 2048
#define HH 64
#define NE 16      // batch elems per block
#define NBLK 32    // 512 / NE

typedef _Float16 half8 __attribute__((ext_vector_type(8)));
typedef _Float16 half4 __attribute__((ext_vector_type(4)));
typedef float f32x4 __attribute__((ext_vector_type(4)));

__device__ __forceinline__ float sigmoid_fast(float x) {
    float e = __expf(-x);
    return __builtin_amdgcn_rcpf(1.0f + e);
}
__device__ __forceinline__ float tanh_fast(float x) {
    float e = __expf(-2.0f * x);
    return fmaf(2.0f, __builtin_amdgcn_rcpf(1.0f + e), -1.0f);
}

// MFMA-based LSTM: 32 blocks x 512 threads, 16 batch elems per block.
// Gate GEMMs [256x64]x[64x16] via mfma_f32_16x16x32_f16.
// Waves 0-3 ("A") own layer-0 unit groups j=w: gates0(t) = Whh0.h0(t-1) (+x,b).
// Waves 4-7 ("B") own layer-1 groups j=w-4: gates1(t-1) = Wih1.h0(t-1) + Whh1.h1(t-2)
// (one-step skew, round-7 pattern) -> single barrier per step.
// C-frag layout (m89-verified): col=lane&15=elem, row-in-tile=(lane>>4)*4+reg;
// gate g of unit u lives in acc[g] reg r of the SAME lane -> lane-local updates.
// A-frag: lane row = l&15, k = 8*(l>>4)+i. B-frag: col = l&15, k = 8*(l>>4)+i
// -> h stored [elem][unit] fp16, XOR-swizzled (byte ^ (e&7)<<4) to avoid the
// 16-way bank conflict of the 128B row stride. h double-buffered (write t&1,
// read (t&1)^1) since A writes h0(t) while B reads h0(t-1) in the same phase.
__global__ __launch_bounds__(512, 2) __attribute__((amdgpu_waves_per_eu(2, 2)))
void lstm_mfma_kernel(const float* __restrict__ x,      // [B,T]
                      const float* __restrict__ w_ih0,  // [256,1]
                      const float* __restrict__ w_hh0,  // [256,64]
                      const float* __restrict__ b_ih0,  // [256]
                      const float* __restrict__ b_hh0,  // [256]
                      const float* __restrict__ w_ih1,  // [256,64]
                      const float* __restrict__ w_hh1,  // [256,64]
                      const float* __restrict__ b_ih1,  // [256]
                      const float* __restrict__ b_hh1,  // [256]
                      const float* __restrict__ w1, const float* __restrict__ b1,
                      const float* __restrict__ w2, const float* __restrict__ b2,
                      const float* __restrict__ w3, const float* __restrict__ b3,
                      float* __restrict__ out)          // [B,10]
{
    const int tid = threadIdx.x;
    const int w   = tid >> 6;       // wave 0..7
    const int l   = tid & 63;
    const bool isA = (w < 4);
    const int j   = w & 3;          // unit group: units [16j, 16j+16)
    const int e   = l & 15;         // elem (B-frag col / C col)
    const int kg  = l >> 4;         // k-group / C row-quad

    // h state: [layer][buf][elem*64+unit] fp16, swizzled. 8 KB.
    __shared__ __align__(16) _Float16 hL[2][2][NE * HH];
    __shared__ float cls1[NE][HH];
    __shared__ float cls2[NE][32];

    // zero h buffers
    for (int i = tid; i < 2 * 2 * NE * HH; i += 512)
        ((_Float16*)hL)[i] = (_Float16)0.0f;

    // ---- weight A-frags (fp16), shared register block for A/B roles ----
    // A-wave: wf[0..7] = Whh0 frags [g][ks]; wf[8..15] zero.
    // B-wave: wf[0..7] = Wih1 frags;  wf[8..15] = Whh1 frags.
    half8 wf[16];
    float bv[16], wx[16];
    {
        const float* W0 = isA ? w_hh0 : w_ih1;
        #pragma unroll
        for (int g = 0; g < 4; ++g) {
            const int row = g * 64 + 16 * j + (l & 15);   // A-frag row = l&15
            #pragma unroll
            for (int ks = 0; ks < 2; ++ks) {
                const int c0 = ks * 32 + 8 * kg;
                half8 v;
                #pragma unroll
                for (int i = 0; i < 8; ++i) v[i] = (_Float16)W0[row * HH + c0 + i];
                wf[g * 2 + ks] = v;
            }
        }
        if (!isA) {
            #pragma unroll
            for (int g = 0; g < 4; ++g) {
                const int row = g * 64 + 16 * j + (l & 15);
                #pragma unroll
                for (int ks = 0; ks < 2; ++ks) {
                    const int c0 = ks * 32 + 8 * kg;
                    half8 v;
                    #pragma unroll
                    for (int i = 0; i < 8; ++i) v[i] = (_Float16)w_hh1[row * HH + c0 + i];
                    wf[8 + g * 2 + ks] = v;
                }
            }
        } else {
            #pragma unroll
            for (int f = 8; f < 16; ++f) {
                half8 v;
                #pragma unroll
                for (int i = 0; i < 8; ++i) v[i] = (_Float16)0.0f;
                wf[f] = v;
            }
        }
        // bias / wih0 per (g, r): C row = g*64 + 16j + 4*kg + r
        #pragma unroll
        for (int g = 0; g < 4; ++g) {
            #pragma unroll
            for (int r = 0; r < 4; ++r) {
                const int row = g * 64 + 16 * j + 4 * kg + r;
                bv[g * 4 + r] = isA ? (b_ih0[row] + b_hh0[row]) : (b_ih1[row] + b_hh1[row]);
                wx[g * 4 + r] = isA ? w_ih0[row] : 0.0f;
            }
        }
    }
    // pin (rounds 1-4 lesson: allocator rematerializes weight loads otherwise)
    #pragma unroll
    for (int i = 0; i < 16; ++i) {
        asm volatile("" : "+v"(wf[i]));
        asm volatile("" : "+v"(bv[i]));
        asm volatile("" : "+v"(wx[i]));
    }

    // per-lane x pointer (elem e); prefetched one step ahead
    const float* xg = x + (size_t)(blockIdx.x * NE + e) * TT;
    float xc = xg[0];

    float cst[4] = {0.0f, 0.0f, 0.0f, 0.0f};   // c-state: 4 units, elem e
    __syncthreads();

    const int swz = (e & 7) << 4;
    char* const hb00 = (char*)&hL[0][0][0];
    char* const hb01 = (char*)&hL[0][1][0];
    char* const hb10 = (char*)&hL[1][0][0];
    char* const hb11 = (char*)&hL[1][1][0];

    for (int t = 0; t <= TT; ++t) {
        const int wb = t & 1;
        float xn = xg[(t + 1 < TT) ? (t + 1) : (TT - 1)];   // prefetch

        const char* h0r = wb ? hb00 : hb01;   // read buf = wb^1
        const char* h1r = wb ? hb10 : hb11;

        half8 hf0 = *(const half8*)(h0r + e * 128 + ((kg * 16) ^ swz));
        half8 hf1 = *(const half8*)(h0r + e * 128 + ((64 + kg * 16) ^ swz));

        f32x4 acc[4];
        #pragma unroll
        for (int g = 0; g < 4; ++g) {
            #pragma unroll
            for (int r = 0; r < 4; ++r)
                acc[g][r] = fmaf(wx[g * 4 + r], xc, bv[g * 4 + r]);
        }

        if (isA) {
            #pragma unroll
            for (int g = 0; g < 4; ++g) {
                acc[g] = __builtin_amdgcn_mfma_f32_16x16x32_f16(wf[g * 2 + 0], hf0, acc[g], 0, 0, 0);
                acc[g] = __builtin_amdgcn_mfma_f32_16x16x32_f16(wf[g * 2 + 1], hf1, acc[g], 0, 0, 0);
            }
        } else {
            half8 hf2 = *(const half8*)(h1r + e * 128 + ((kg * 16) ^ swz));
            half8 hf3 = *(const half8*)(h1r + e * 128 + ((64 + kg * 16) ^ swz));
            #pragma unroll
            for (int g = 0; g < 4; ++g) {
                acc[g] = __builtin_amdgcn_mfma_f32_16x16x32_f16(wf[g * 2 + 0], hf0, acc[g], 0, 0, 0);
                acc[g] = __builtin_amdgcn_mfma_f32_16x16x32_f16(wf[g * 2 + 1], hf1, acc[g], 0, 0, 0);
                acc[g] = __builtin_amdgcn_mfma_f32_16x16x32_f16(wf[8 + g * 2 + 0], hf2, acc[g], 0, 0, 0);
                acc[g] = __builtin_amdgcn_mfma_f32_16x16x32_f16(wf[8 + g * 2 + 1], hf3, acc[g], 0, 0, 0);
            }
        }

        // activations + state update (lane-local: 4 units x elem e)
        half4 hv;
        #pragma unroll
        for (int r = 0; r < 4; ++r) {
            float gi = sigmoid_fast(acc[0][r]);
            float gf = sigmoid_fast(acc[1][r]);
            float gg = tanh_fast(acc[2][r]);
            float go = sigmoid_fast(acc[3][r]);
            float c  = fmaf(gf, cst[r], gi * gg);
            float h  = go * tanh_fast(c);
            if (!isA && t == 0) { c = 0.0f; h = 0.0f; }   // enforce h1(-1)=0
            cst[r] = c;
            hv[r]  = (_Float16)h;
        }

        // write h (4 contiguous units, 8B, swizzled)
        {
            char* hwv = isA ? (wb ? hb01 : hb00) : (wb ? hb11 : hb10);
            const int u0 = 16 * j + 4 * kg;
            *(half4*)(hwv + e * 128 + ((u0 * 2) ^ swz)) = hv;
        }
        xc = xn;
        __syncthreads();
    }

    // ---- classifier head; h_last = h1(TT-1) in buf 0 (TT even) ----
    const char* h1f = hb10;
    #pragma unroll
    for (int p = 0; p < 2; ++p) {
        const int ee = w + 8 * p;
        const int esw = (ee & 7) << 4;
        float a = b1[l];
        #pragma unroll 8
        for (int k = 0; k < HH; ++k) {
            _Float16 hk = *(const _Float16*)(h1f + ee * 128 + ((k * 2) ^ esw));
            a = fmaf(w1[l * HH + k], (float)hk, a);
        }
        cls1[ee][l] = fmaxf(a, 0.0f);
        __syncthreads();
        if (l < 32) {
            float a2 = b2[l];
            #pragma unroll 8
            for (int k = 0; k < HH; ++k) a2 = fmaf(w2[l * HH + k], cls1[ee][k], a2);
            cls2[ee][l] = fmaxf(a2, 0.0f);
        }
        __syncthreads();
        if (l < 10) {
            float a3 = b3[l];
            #pragma unroll
            for (int k = 0; k < 32; ++k) a3 = fmaf(w3[l * 32 + k], cls2[ee][k], a3);
            out[(blockIdx.x * NE + ee) * 10 + l] = a3;
        }
        __syncthreads();
    }
}

extern "C" void kernel_launch(void* const* d_in, const int* in_sizes, int n_in,
                              void* d_out, int out_size, void* d_ws, size_t ws_size,
                              hipStream_t stream) {
    const float* x     = (const float*)d_in[0];
    const float* w_ih0 = (const float*)d_in[1];
    const float* w_hh0 = (const float*)d_in[2];
    const float* b_ih0 = (const float*)d_in[3];
    const float* b_hh0 = (const float*)d_in[4];
    const float* w_ih1 = (const float*)d_in[5];
    const float* w_hh1 = (const float*)d_in[6];
    const float* b_ih1 = (const float*)d_in[7];
    const float* b_hh1 = (const float*)d_in[8];
    const float* w1    = (const float*)d_in[9];
    const float* b1    = (const float*)d_in[10];
    const float* w2    = (const float*)d_in[11];
    const float* b2    = (const float*)d_in[12];
    const float* w3    = (const float*)d_in[13];
    const float* b3    = (const float*)d_in[14];
    float* out = (float*)d_out;

    lstm_mfma_kernel<<<NBLK, 512, 0, stream>>>(x, w_ih0, w_hh0, b_ih0, b_hh0,
                                               w_ih1, w_hh1, b_ih1, b_hh1,
                                               w1, b1, w2, b2, w3, b3, out);
}